// Round 13
// baseline (196.062 us; speedup 1.0000x reference)
//
#include <hip/hip_runtime.h>

// InternalInteraction: out[b,j,d] = sum_i [ relu((x_i*x_j)@W1^T + b1) @ W2^T + b2 ]
// Factored: hsum[b,j,h] = sum_i relu((x_i*x_j)@W1^T + b1); out = hsum@W2^T + 16*b2.
// B=2048, A=16, D=128, H=512. Storage fp32; MFMA in bf16.
//
// Round-16 structure (vs r14 = r8-class best at 87.0us interact / 148.3 total):
//  - POST-MORTEM r15: per-n liveness cut made spill WORSE (WRITE 19.5->63MB,
//    87->130us). Ledger now 6/6 regressions from restructuring the GEMM1
//    loop (r9 r10 r11 r12 r13 r15). The r8 loop shape is load-bearing and
//    is kept BYTE-IDENTICAL here.
//  - NEW ATTACK SURFACE: the ~55-60us constant gap between interact and
//    total dur_us (stable across all 16 rounds). Part harness, part OUR
//    convert_weights dispatch graph-serialized before interact. This round
//    DELETES that dispatch: W1 is read as fp32 + cast in the prologue
//    (2x f32x4 -> bf16x8 per fragment, once per block, outside the loop);
//    W2 is read as fp32 + cast in the GEMM2 tail. Same bf16-rounded
//    values -> bit-identical math -> absmax unchanged. W1/W2 are L2/L3
//    resident (256KB each fp32) so HBM fetch barely moves.
//  - Diagnostic: total drops ~8-15us => dispatch boundary was real cost.
//    Total unchanged => gap is pure harness; r8-class confirmed final.
//  - Everything else = r8: SYMMETRY CUT (9 shift tiles, dlt & 16-dlt equal
//    row-rotated; aligned add + runtime-idx ds_bpermute rotated add),
//    swapped-operand GEMM1 (C rows=h, cols=j), unroll-1 dlt loop,
//    512 thr / 8 waves / 64 h per wave, (512,4), f32 xs staging,
//    hs aliasing dead ps, 4 barriers/block.

#define BATCH 2048
#define AA 16
#define DD 128
#define HH 512

typedef __bf16 bf16;
typedef bf16  bf16x4 __attribute__((ext_vector_type(4)));
typedef bf16  bf16x8 __attribute__((ext_vector_type(8)));
typedef float f32x4  __attribute__((ext_vector_type(4)));

__device__ inline f32x4 splat4(float v) { f32x4 r = {v, v, v, v}; return r; }

// pull float from another lane: idx = source_lane * 4 (byte index)
__device__ inline float bperm_f32(int idx, float v) {
    return __int_as_float(__builtin_amdgcn_ds_bpermute(idx, __float_as_int(v)));
}

// load 8 fp32 and round to bf16x8 (same values the old convert kernel made)
__device__ inline bf16x8 load_w_bf16x8(const float* __restrict__ p) {
    f32x4 lo = *(const f32x4*)p;
    f32x4 hi = *(const f32x4*)(p + 4);
    bf16x8 o;
    o[0] = (bf16)lo[0]; o[1] = (bf16)lo[1]; o[2] = (bf16)lo[2]; o[3] = (bf16)lo[3];
    o[4] = (bf16)hi[0]; o[5] = (bf16)hi[1]; o[6] = (bf16)hi[2]; o[7] = (bf16)hi[3];
    return o;
}

// One block per batch. 512 threads = 8 waves; wave w owns H cols [w*64, w*64+64).
__global__ __launch_bounds__(512, 4)
void interact_kernel(const float* __restrict__ x,    // [B, A, D] fp32
                     const float* __restrict__ W1,   // [H, D] fp32
                     const float* __restrict__ b1,   // [H]
                     const float* __restrict__ W2,   // [D, H] fp32
                     const float* __restrict__ b2,   // [D]
                     float* __restrict__ out)        // [B, A, D] fp32
{
    // xs: x_b in f32, row stride 136 (544 B)
    __shared__ float xs[16][136];                               // 8704 B
    // ps: 9 shift-tiles [dlt][j][136] bf16; tile dlt row j = x_{(j+dlt)&15}*x_j.
    //     row stride 272 B -> frag b128 reads uniform over 8 bank-slots.
    // hs: GEMM2 staging [16][520] bf16 (16640 B) -- ALIASES ps (dead by then).
    __shared__ __align__(16) unsigned char smem_raw[9 * 16 * 136 * 2];  // 39168 B
    bf16 (*ps)[16][136] = reinterpret_cast<bf16(*)[16][136]>(smem_raw);
    bf16 (*hs)[520]     = reinterpret_cast<bf16(*)[520]>(smem_raw);

    const int b    = blockIdx.x;
    const int tid  = threadIdx.x;
    const int wave = tid >> 6;    // 0..7
    const int lane = tid & 63;
    const int quad = lane >> 4;   // 0..3
    const int col  = lane & 15;   // 0..15

    // build-phase coordinates: thread owns (jrow, dq..dq+4)
    const int jrow = tid >> 5;          // 0..15
    const int dq   = (tid & 31) * 4;    // 0..124

    // ---- stage x_b into LDS (f32); keep own 4-float slice in regs ----
    f32x4 xj;
    {
        const float* src = x + (size_t)b * (AA * DD) + jrow * DD + dq;
        xj = *(const f32x4*)src;
        *(f32x4*)(&xs[jrow][dq]) = xj;
    }

    // ---- W1 fragments: fp32 loads + in-register bf16 round (64 regs) ----
    // Used as MFMA arg0 (A-operand): lane holds W1[h = n*16+col][k-slice].
    bf16x8 w1f[4][4];
    f32x4  bias4[4];   // C-seed: b1[h0 + quad*4 + r] per reg r (C rows = h)
#pragma unroll
    for (int n = 0; n < 4; ++n) {
        int h    = wave * 64 + n * 16 + col;
        bias4[n] = *(const f32x4*)(b1 + wave * 64 + n * 16 + quad * 4);
#pragma unroll
        for (int kk = 0; kk < 4; ++kk)
            w1f[n][kk] = load_w_bf16x8(W1 + h * DD + kk * 32 + quad * 8);
    }

    f32x4 hsum[4];
#pragma unroll
    for (int n = 0; n < 4; ++n) hsum[n] = splat4(0.f);

    __syncthreads();   // xs complete

    // ---- build 9 shift tiles: ps[dlt][j][d] = bf16(x_{(j+dlt)&15}[d]*x_j[d]) ----
#pragma unroll
    for (int dlt = 0; dlt < 9; ++dlt) {
        f32x4 xi = *(f32x4*)(&xs[(jrow + dlt) & 15][dq]);
        bf16x4 pr;
#pragma unroll
        for (int e = 0; e < 4; ++e) pr[e] = (bf16)(xj[e] * xi[e]);
        *(bf16x4*)(&ps[dlt][jrow][dq]) = pr;
    }
    __syncthreads();   // all tiles ready; no barriers until GEMM2 staging

    // ---- GEMM1 over 9 shift tiles (SWAPPED operands: C rows=h, cols=j) ----
    // BYTE-IDENTICAL to r8/r14 (the proven no-spill shape; see ledger).
    // arg0 = w1f (A rows = h-sub = col), arg1 = af (B cols = j = col).
    // C/D: lane(q,c) holds v[h = base + n*16 + q*4 + r][j = c].
    // hsum[j] = sum_{d=0..8} v_d[j] + sum_{d=1..7} v_d[(j-d)&15]; the second
    // term is a pure lane-rotation within the 16-lane col group -> one
    // runtime-indexed ds_bpermute per (n,r), same register. unroll 1!
#pragma unroll 1
    for (int dlt = 0; dlt < 9; ++dlt) {
        bf16x8 af[4];
#pragma unroll
        for (int kk = 0; kk < 4; ++kk)
            af[kk] = *(bf16x8*)(&ps[dlt][col][kk * 32 + quad * 8]);

        f32x4 v[4];
#pragma unroll
        for (int n = 0; n < 4; ++n)
            v[n] = __builtin_amdgcn_mfma_f32_16x16x32_bf16(
                w1f[n][0], af[0], bias4[n], 0, 0, 0);
#pragma unroll
        for (int kk = 1; kk < 4; ++kk)
#pragma unroll
            for (int n = 0; n < 4; ++n)
                v[n] = __builtin_amdgcn_mfma_f32_16x16x32_bf16(
                    w1f[n][kk], af[kk], v[n], 0, 0, 0);

        // relu in place
#pragma unroll
        for (int n = 0; n < 4; ++n)
#pragma unroll
            for (int r = 0; r < 4; ++r)
                v[n][r] = fmaxf(v[n][r], 0.f);

        // aligned add
#pragma unroll
        for (int n = 0; n < 4; ++n)
#pragma unroll
            for (int r = 0; r < 4; ++r)
                hsum[n][r] += v[n][r];

        // rotated add (tile 16-dlt): lane j takes lane (j-dlt)&15, same quad
        if (dlt >= 1 && dlt <= 7) {
            const int idx = ((quad << 4) | ((col - dlt) & 15)) << 2;
#pragma unroll
            for (int n = 0; n < 4; ++n)
#pragma unroll
                for (int r = 0; r < 4; ++r)
                    hsum[n][r] += bperm_f32(idx, v[n][r]);
        }
    }

    __syncthreads();   // all ps reads done before hs overwrites the region

    // ---- hsum -> LDS (bf16) for GEMM2 A-operand re-layout ----
    // Transposed C layout: lane(q,c) holds hsum[j=c][h = w*64+n*16+q*4+r]
    // -> contiguous in h: one bf16x4 store per n.
#pragma unroll
    for (int n = 0; n < 4; ++n) {
        bf16x4 o;
#pragma unroll
        for (int r = 0; r < 4; ++r) o[r] = (bf16)hsum[n][r];
        *(bf16x4*)(&hs[col][wave * 64 + n * 16 + quad * 4]) = o;
    }

    __syncthreads();

    // ---- GEMM2: out[j,d] = hsum[j,:] @ W2^T + 16*b2 ----
    // M=16 (j), N=16 per wave (d = wave*16 + col), K=512 (h). W2 is [D,H] fp32;
    // bw is loaded fp32 + rounded to bf16 in-register (same values as the
    // old convert kernel produced).
    const int d = wave * 16 + col;
    f32x4 acc2 = splat4(16.f * b2[d]);

#pragma unroll
    for (int ks = 0; ks < 16; ++ks) {
        int h0 = ks * 32 + quad * 8;
        bf16x8 a2 = *(bf16x8*)(&hs[col][h0]);
        bf16x8 bw = load_w_bf16x8(W2 + d * HH + h0);
        acc2 = __builtin_amdgcn_mfma_f32_16x16x32_bf16(a2, bw, acc2, 0, 0, 0);
    }

#pragma unroll
    for (int r = 0; r < 4; ++r) {
        int j = quad * 4 + r;
        out[(size_t)b * (AA * DD) + j * DD + d] = acc2[r];
    }
}

extern "C" void kernel_launch(void* const* d_in, const int* in_sizes, int n_in,
                              void* d_out, int out_size, void* d_ws, size_t ws_size,
                              hipStream_t stream)
{
    const float* x  = (const float*)d_in[0];  // [2048,16,128]
    const float* W1 = (const float*)d_in[1];  // [512,128]
    const float* b1 = (const float*)d_in[2];  // [512]
    const float* W2 = (const float*)d_in[3];  // [128,512]
    const float* b2 = (const float*)d_in[4];  // [128]
    float* out = (float*)d_out;

    // single dispatch: weight conversion folded into interact's loads
    interact_kernel<<<BATCH, 512, 0, stream>>>(x, W1, b1, W2, b2, out);
}